// Round 4
// baseline (52.180 us; speedup 1.0000x reference)
//
#include <hip/hip_runtime.h>

#define UNITS   4096
#define IN_DIM  4096
#define LEVELS  16
#define NGROUPS 32
#define BATCH   16

#define UPW    2                   // units per wave
#define WAVES  4
#define UPB    (UPW * WAVES)       // 8 units per block
#define KSPLIT 4
#define KSLICE (IN_DIM / KSPLIT)   // 1024
#define KQ     256                 // 64 lanes * 4 floats
#define NITER  (KSLICE / KQ)       // 4

// Load weights for iteration IT into register buffer BUF.
// Used only under full unroll -> BUF is compile-time, arrays stay in VGPRs.
#define LOADW(IT, BUF)                                                        \
    {                                                                         \
        const int k_ = kbase + (IT) * KQ;                                     \
        const int g_ = k_ >> 7;                                               \
        _Pragma("unroll")                                                     \
        for (int u = 0; u < UPW; ++u) {                                       \
            const size_t off_ = (size_t)(o0 + u) * IN_DIM + k_;               \
            idxb[BUF][u] = *reinterpret_cast<const int4*>(&indices[off_]);    \
            rb[BUF][u]   = *reinterpret_cast<const float4*>(&residual[off_]); \
            sb[BUF][u]   = scales[(o0 + u) * NGROUPS + g_];                   \
        }                                                                     \
    }

__global__ __launch_bounds__(256, 4)
void turbo_dense_kernel(const float* __restrict__ inputs,
                        const float* __restrict__ codebooks,
                        const float* __restrict__ scales,
                        const float* __restrict__ residual,
                        const float* __restrict__ bias,
                        const int*   __restrict__ indices,
                        float* __restrict__ out)
{
    __shared__ float cb[UPB * LEVELS];   // 8 units * 16 levels = 512 B

    const int tid  = threadIdx.x;
    const int bx   = blockIdx.x;
    const int ub   = bx & 511;            // unit-group 0..511
    const int ks   = bx >> 9;             // k-slice 0..3
    const int o_block = ub * UPB;

    const int wave  = tid >> 6;
    const int lane  = tid & 63;
    const int o0    = o_block + wave * UPW;
    const int kbase = ks * KSLICE + lane * 4;

    // register double-buffer for the weight stream
    int4   idxb[2][UPW];
    float4 rb[2][UPW];
    float  sb[2][UPW];

    LOADW(0, 0);                          // prefetch iter 0 (overlaps cb+sync)
    if (tid < UPB * LEVELS) cb[tid] = codebooks[o_block * LEVELS + tid];
    __syncthreads();                      // only barrier in the kernel

    float acc[BATCH * UPW];
    #pragma unroll
    for (int i = 0; i < BATCH * UPW; ++i) acc[i] = 0.f;

    const float* cbw = &cb[wave * UPW * LEVELS];

    #pragma unroll
    for (int it = 0; it < NITER; ++it) {
        const int cur = it & 1;
        if (it + 1 < NITER) { LOADW(it + 1, cur ^ 1) }   // prefetch next iter

        // dequantize current buffer (LDS gather + fma)
        float w[UPW][4];
        #pragma unroll
        for (int u = 0; u < UPW; ++u) {
            w[u][0] = fmaf(cbw[u * LEVELS + idxb[cur][u].x], sb[cur][u], rb[cur][u].x);
            w[u][1] = fmaf(cbw[u * LEVELS + idxb[cur][u].y], sb[cur][u], rb[cur][u].y);
            w[u][2] = fmaf(cbw[u * LEVELS + idxb[cur][u].z], sb[cur][u], rb[cur][u].z);
            w[u][3] = fmaf(cbw[u * LEVELS + idxb[cur][u].w], sb[cur][u], rb[cur][u].w);
        }

        // batch FMAs (inputs are 256 KB total -> L1/L2-hot)
        const int k = kbase + it * KQ;
        #pragma unroll
        for (int b = 0; b < BATCH; ++b) {
            const float4 in4 = *reinterpret_cast<const float4*>(&inputs[b * IN_DIM + k]);
            #pragma unroll
            for (int u = 0; u < UPW; ++u) {
                float a = acc[b * UPW + u];
                a = fmaf(in4.x, w[u][0], a);
                a = fmaf(in4.y, w[u][1], a);
                a = fmaf(in4.z, w[u][2], a);
                a = fmaf(in4.w, w[u][3], a);
                acc[b * UPW + u] = a;
            }
        }
    }

    // fold-reduce: 32 accs over 64 lanes -> 5 halving rounds + 1 pair add
#define FOLD(S, N)                                         \
    {                                                      \
        const bool hi = (lane & (S)) != 0;                 \
        _Pragma("unroll")                                  \
        for (int t = 0; t < (N) / 2; ++t) {                \
            float a  = acc[2 * t];                         \
            float b2 = acc[2 * t + 1];                     \
            float send = hi ? a : b2;                      \
            float recv = __shfl_xor(send, (S));            \
            acc[t] = (hi ? b2 : a) + recv;                 \
        }                                                  \
    }
    FOLD(1, 32)
    FOLD(2, 16)
    FOLD(4, 8)
    FOLD(8, 4)
    FOLD(16, 2)
#undef FOLD
    // acc[0] now = total over lanes sharing bit5, for orig index (lane&31)
    acc[0] += __shfl_xor(acc[0], 32);     // full 64-lane sum (duplicated hi/lo)

    if (lane < 32) {
        const int i  = lane;              // i = b*UPW + u
        const int b_ = i >> 1;
        const int u_ = i & 1;
        float v = acc[0];
        if (ks == 0) v += bias[o0 + u_];
        atomicAdd(&out[b_ * UNITS + o0 + u_], v);
    }
}

extern "C" void kernel_launch(void* const* d_in, const int* in_sizes, int n_in,
                              void* d_out, int out_size, void* d_ws, size_t ws_size,
                              hipStream_t stream)
{
    const float* inputs    = (const float*)d_in[0];
    const float* codebooks = (const float*)d_in[1];
    const float* scales    = (const float*)d_in[2];
    const float* residual  = (const float*)d_in[3];
    const float* bias      = (const float*)d_in[4];
    const int*   indices   = (const int*)d_in[5];
    float* out = (float*)d_out;

    // out is accumulated via atomics -> must start from zero every call
    hipMemsetAsync(d_out, 0, (size_t)out_size * sizeof(float), stream);

    dim3 grid((UNITS / UPB) * KSPLIT);   // 512 unit-groups * 4 k-slices = 2048
    dim3 block(256);
    turbo_dense_kernel<<<grid, block, 0, stream>>>(inputs, codebooks, scales,
                                                   residual, bias, indices, out);
}

// Round 5
// 43.260 us; speedup vs baseline: 1.2062x; 1.2062x over previous
//
#include <hip/hip_runtime.h>

#define UNITS   4096
#define IN_DIM  4096
#define LEVELS  16
#define NGROUPS 32
#define BATCH   16

#define KCHUNK  512
#define NCHUNK  2            // chunks per block
#define KQSPLIT 4            // blocks along k
#define LDS_STRIDE 536       // shorts per o-row (512 + pad, 16B-aligned)

typedef __attribute__((ext_vector_type(8))) short bf16x8;
typedef __attribute__((ext_vector_type(4))) float f32x4;

__device__ __forceinline__ unsigned int f2bf(float f) {
    unsigned int u = __float_as_uint(f);
    u += 0x7FFF + ((u >> 16) & 1);
    return u >> 16;   // low 16 bits valid
}

#define ELEM4I(v, j) ((j)==0?(v).x:((j)==1?(v).y:((j)==2?(v).z:(v).w)))

// ---------- kernel 1: inputs f32[16][4096] -> A-fragment bf16 layout ----------
// A_frag[ks(128)][lane(64)][8] : lane holds A[m=lane&15][k=ks*32+(lane>>4)*8+j]
__global__ void aconv_kernel(const float* __restrict__ inputs,
                             unsigned short* __restrict__ A_frag)
{
    const int slot = blockIdx.x * 256 + threadIdx.x;   // 0..8191
    const int ks = slot >> 6, lane = slot & 63;
    const int m  = lane & 15;
    const int kk = ks * 32 + ((lane >> 4) << 3);
    const float4 a = *reinterpret_cast<const float4*>(&inputs[m * IN_DIM + kk]);
    const float4 b = *reinterpret_cast<const float4*>(&inputs[m * IN_DIM + kk + 4]);
    uint4 pk;
    pk.x = f2bf(a.x) | (f2bf(a.y) << 16);
    pk.y = f2bf(a.z) | (f2bf(a.w) << 16);
    pk.z = f2bf(b.x) | (f2bf(b.y) << 16);
    pk.w = f2bf(b.z) | (f2bf(b.w) << 16);
    *reinterpret_cast<uint4*>(&A_frag[(size_t)slot * 8]) = pk;
}

// ---------- kernel 2: fused dequant (burst->LDS bf16) + MFMA ----------
__global__ __launch_bounds__(256, 4)
void turbo_mfma_kernel(const float* __restrict__ codebooks,
                       const float* __restrict__ scales,
                       const float* __restrict__ residual,
                       const float* __restrict__ bias,
                       const int*   __restrict__ indices,
                       const unsigned short* __restrict__ A_frag,
                       float* __restrict__ out)
{
    __shared__ float cb[16 * LEVELS];                 // 1 KiB
    __shared__ unsigned short Wlds[16 * LDS_STRIDE];  // 16.75 KiB
    __shared__ float red[3][64][4];                   // 3 KiB

    const int tid  = threadIdx.x;
    const int wave = tid >> 6, lane = tid & 63;
    const int ot   = blockIdx.x >> 2;                 // 0..255 (16-unit tile)
    const int kq   = blockIdx.x & 3;                  // 0..3
    const int obase = ot * 16;

    cb[tid] = codebooks[obase * LEVELS + tid];
    __syncthreads();

    f32x4 acc = {0.f, 0.f, 0.f, 0.f};

    for (int c = 0; c < NCHUNK; ++c) {
        const int kb = kq * (KCHUNK * NCHUNK) + c * KCHUNK;
        const int kk = lane * 8;

        // --- burst: 16 independent 16B loads (4 o-rows x (2 idx4 + 2 res4))
        int4   i4[4][2];
        float4 r4[4][2];
        float  sc[4];
        #pragma unroll
        for (int u = 0; u < 4; ++u) {
            const int o = obase + wave * 4 + u;
            const size_t off = (size_t)o * IN_DIM + kb + kk;
            i4[u][0] = *reinterpret_cast<const int4*>(&indices[off]);
            i4[u][1] = *reinterpret_cast<const int4*>(&indices[off + 4]);
            r4[u][0] = *reinterpret_cast<const float4*>(&residual[off]);
            r4[u][1] = *reinterpret_cast<const float4*>(&residual[off + 4]);
            sc[u]    = scales[o * NGROUPS + ((kb + kk) >> 7)];
        }

        // --- dequant 8 elems per o-row, pack bf16, write 16B to LDS
        #pragma unroll
        for (int u = 0; u < 4; ++u) {
            const int o_l = wave * 4 + u;
            const float* cbr = &cb[o_l * LEVELS];
            unsigned int w16[8];
            #pragma unroll
            for (int j = 0; j < 8; ++j) {
                const int   ij = (j < 4) ? ELEM4I(i4[u][0], j) : ELEM4I(i4[u][1], j - 4);
                const float rj = (j < 4) ? ELEM4I(r4[u][0], j) : ELEM4I(r4[u][1], j - 4);
                w16[j] = f2bf(fmaf(cbr[ij], sc[u], rj));
            }
            uint4 pk;
            pk.x = w16[0] | (w16[1] << 16);
            pk.y = w16[2] | (w16[3] << 16);
            pk.z = w16[4] | (w16[5] << 16);
            pk.w = w16[6] | (w16[7] << 16);
            *reinterpret_cast<uint4*>(&Wlds[o_l * LDS_STRIDE + kk]) = pk;
        }
        __syncthreads();

        // --- MFMA: wave handles 4 of the 16 K-steps of this chunk
        #pragma unroll
        for (int i = 0; i < 4; ++i) {
            const int ks_l = wave * 4 + i;
            const int ksg  = (kb >> 5) + ks_l;
            bf16x8 a = *reinterpret_cast<const bf16x8*>(
                &A_frag[((size_t)ksg * 64 + lane) * 8]);
            bf16x8 b = *reinterpret_cast<const bf16x8*>(
                &Wlds[(lane & 15) * LDS_STRIDE + ks_l * 32 + ((lane >> 4) << 3)]);
            acc = __builtin_amdgcn_mfma_f32_16x16x32_bf16(a, b, acc, 0, 0, 0);
        }
        __syncthreads();   // before next chunk overwrites Wlds
    }

    // --- reduce the 4 waves' disjoint-K partials, then one atomic set
    if (wave > 0)
        *reinterpret_cast<f32x4*>(&red[wave - 1][lane][0]) = acc;
    __syncthreads();
    if (wave == 0) {
        #pragma unroll
        for (int wv = 0; wv < 3; ++wv)
            acc += *reinterpret_cast<const f32x4*>(&red[wv][lane][0]);
        const int col = obase + (lane & 15);
        const float bv = (kq == 0) ? bias[col] : 0.f;
        #pragma unroll
        for (int q = 0; q < 4; ++q) {
            const int m = ((lane >> 4) << 2) + q;   // C/D row map [m89/m91]
            atomicAdd(&out[m * UNITS + col], acc[q] + bv);
        }
    }
}

// ---------- fallback (proven 48 us kernel) if workspace is too small ----------
__global__ __launch_bounds__(256, 4)
void fallback_kernel(const float* __restrict__ inputs,
                     const float* __restrict__ codebooks,
                     const float* __restrict__ scales,
                     const float* __restrict__ residual,
                     const float* __restrict__ bias,
                     const int*   __restrict__ indices,
                     float* __restrict__ out)
{
    __shared__ float cb[16 * LEVELS];
    const int tid = threadIdx.x;
    const int ub = blockIdx.x & 255, ks = blockIdx.x >> 8;
    const int o_block = ub * 16;
    cb[tid] = codebooks[o_block * LEVELS + tid];
    __syncthreads();
    const int wave = tid >> 6, lane = tid & 63;
    const int o0 = o_block + wave * 4;
    const int k = ks * 256 + lane * 4;
    const int g = k >> 7;
    int4 idx[4]; float4 r[4]; float s[4];
    #pragma unroll
    for (int u = 0; u < 4; ++u) {
        const size_t off = (size_t)(o0 + u) * IN_DIM + k;
        idx[u] = *reinterpret_cast<const int4*>(&indices[off]);
        r[u]   = *reinterpret_cast<const float4*>(&residual[off]);
        s[u]   = scales[(o0 + u) * NGROUPS + g];
    }
    const float* cbw = &cb[wave * 4 * LEVELS];
    float w[4][4];
    #pragma unroll
    for (int u = 0; u < 4; ++u) {
        w[u][0] = fmaf(cbw[u * LEVELS + idx[u].x], s[u], r[u].x);
        w[u][1] = fmaf(cbw[u * LEVELS + idx[u].y], s[u], r[u].y);
        w[u][2] = fmaf(cbw[u * LEVELS + idx[u].z], s[u], r[u].z);
        w[u][3] = fmaf(cbw[u * LEVELS + idx[u].w], s[u], r[u].w);
    }
    float acc[64];
    #pragma unroll
    for (int b = 0; b < BATCH; ++b) {
        const float4 in4 = *reinterpret_cast<const float4*>(&inputs[b * IN_DIM + k]);
        #pragma unroll
        for (int u = 0; u < 4; ++u) {
            float a = in4.x * w[u][0];
            a = fmaf(in4.y, w[u][1], a);
            a = fmaf(in4.z, w[u][2], a);
            a = fmaf(in4.w, w[u][3], a);
            acc[b * 4 + u] = a;
        }
    }
#define FOLD(S, N)                                         \
    {                                                      \
        const bool hi = (lane & (S)) != 0;                 \
        _Pragma("unroll")                                  \
        for (int t = 0; t < (N) / 2; ++t) {                \
            float a  = acc[2 * t];                         \
            float b2 = acc[2 * t + 1];                     \
            float send = hi ? a : b2;                      \
            float recv = __shfl_xor(send, (S));            \
            acc[t] = (hi ? b2 : a) + recv;                 \
        }                                                  \
    }
    FOLD(1, 64) FOLD(2, 32) FOLD(4, 16) FOLD(8, 8) FOLD(16, 4) FOLD(32, 2)
#undef FOLD
    const int b_ = lane >> 2, u_ = lane & 3;
    float v = acc[0];
    if (ks == 0) v += bias[o0 + u_];
    atomicAdd(&out[b_ * UNITS + o0 + u_], v);
}

extern "C" void kernel_launch(void* const* d_in, const int* in_sizes, int n_in,
                              void* d_out, int out_size, void* d_ws, size_t ws_size,
                              hipStream_t stream)
{
    const float* inputs    = (const float*)d_in[0];
    const float* codebooks = (const float*)d_in[1];
    const float* scales    = (const float*)d_in[2];
    const float* residual  = (const float*)d_in[3];
    const float* bias      = (const float*)d_in[4];
    const int*   indices   = (const int*)d_in[5];
    float* out = (float*)d_out;

    hipMemsetAsync(d_out, 0, (size_t)out_size * sizeof(float), stream);

    const size_t need = (size_t)128 * 64 * 8 * sizeof(unsigned short); // 128 KiB
    if (ws_size >= need) {
        unsigned short* A_frag = (unsigned short*)d_ws;
        aconv_kernel<<<32, 256, 0, stream>>>(inputs, A_frag);
        turbo_mfma_kernel<<<256 * KQSPLIT, 256, 0, stream>>>(
            codebooks, scales, residual, bias, indices, A_frag, out);
    } else {
        fallback_kernel<<<256 * 16, 256, 0, stream>>>(
            inputs, codebooks, scales, residual, bias, indices, out);
    }
}

// Round 6
// 32.740 us; speedup vs baseline: 1.5938x; 1.3213x over previous
//
#include <hip/hip_runtime.h>

#define UNITS   4096
#define IN_DIM  4096
#define LEVELS  16
#define NGROUPS 32
#define BATCH   16

#define OTILE  16
#define KSPLIT 4
#define KSTEP  128                 // == GROUP -> one scale per (o, iter)
#define NIT    8                   // (IN_DIM/KSPLIT)/KSTEP
#define WB_S   136                 // Wb stride in shorts (128 + 8 pad)

typedef __attribute__((ext_vector_type(8))) short bf16x8;
typedef __attribute__((ext_vector_type(4))) float f32x4;

__device__ __forceinline__ unsigned f2bf(float f) {
    unsigned u = __float_as_uint(f);
    u += 0x7FFF + ((u >> 16) & 1);
    return u >> 16;
}

__device__ __forceinline__ void gload16(const void* g, void* l) {
    __builtin_amdgcn_global_load_lds(
        (const __attribute__((address_space(1))) void*)g,
        (__attribute__((address_space(3))) void*)l, 16, 0, 0);
}

#define ELEM4I(v, j) ((j)==0?(v).x:((j)==1?(v).y:((j)==2?(v).z:(v).w)))

// ---------- kernel 1: inputs f32[16][4096] -> A-fragment bf16 layout ----------
// A_frag[ksg(128)][lane(64)][8] : lane holds A[m=lane&15][k=ksg*32+(lane>>4)*8+j]
__global__ void aconv_kernel(const float* __restrict__ inputs,
                             unsigned short* __restrict__ A_frag)
{
    const int slot = blockIdx.x * 256 + threadIdx.x;   // 0..8191
    const int ks = slot >> 6, lane = slot & 63;
    const int m  = lane & 15;
    const int kk = ks * 32 + ((lane >> 4) << 3);
    const float4 a = *reinterpret_cast<const float4*>(&inputs[m * IN_DIM + kk]);
    const float4 b = *reinterpret_cast<const float4*>(&inputs[m * IN_DIM + kk + 4]);
    uint4 pk;
    pk.x = f2bf(a.x) | (f2bf(a.y) << 16);
    pk.y = f2bf(a.z) | (f2bf(a.w) << 16);
    pk.z = f2bf(b.x) | (f2bf(b.y) << 16);
    pk.w = f2bf(b.z) | (f2bf(b.w) << 16);
    *reinterpret_cast<uint4*>(&A_frag[(size_t)slot * 8]) = pk;
}

// ---------- kernel 2: async-staged dequant + MFMA ----------
__global__ __launch_bounds__(256, 4)
void turbo_mfma2(const float* __restrict__ codebooks,
                 const float* __restrict__ scales,
                 const float* __restrict__ residual,
                 const float* __restrict__ bias,
                 const int*   __restrict__ indices,
                 const unsigned short* __restrict__ A_frag,
                 float* __restrict__ out)
{
    __shared__ int   Idx[2][OTILE * KSTEP];                 // 16 KiB
    __shared__ float Res[2][OTILE * KSTEP];                 // 16 KiB
    __shared__ __align__(16) unsigned short Wb[OTILE * WB_S]; // 4.25 KiB (reused as red)
    __shared__ float cb[OTILE * LEVELS];                    // 1 KiB
    __shared__ float scs[OTILE][NIT];                       // 0.5 KiB
    // total 37.75 KiB -> 4 blocks/CU

    const int tid = threadIdx.x;
    const int w   = tid >> 6, l = tid & 63;

    // XCD-bijective swizzle: nwg=1024, 8 XCDs, q=128
    const int bx  = blockIdx.x;
    const int bxs = (bx & 7) * 128 + (bx >> 3);
    const int ot  = bxs >> 2;                  // 0..255
    const int kq  = bxs & 3;                   // 0..3
    const int obase   = ot * OTILE;
    const int kslice0 = kq * (NIT * KSTEP);    // kq*1024

    // ---- prologue: cb + scales to LDS, A-fragments to registers
    cb[tid] = codebooks[obase * LEVELS + tid];                 // 256 == OTILE*LEVELS
    if (tid < OTILE * NIT)
        scs[tid >> 3][tid & 7] =
            scales[(obase + (tid >> 3)) * NGROUPS + kq * NIT + (tid & 7)];

    uint4 aA[NIT];
    #pragma unroll
    for (int it = 0; it < NIT; ++it) {
        const int ksg = (kslice0 >> 5) + it * 4 + w;
        aA[it] = *reinterpret_cast<const uint4*>(&A_frag[((size_t)ksg * 64 + l) * 8]);
    }

    // stage chunk layout: chunk c (1KB, 256 ints) = o-rows [2c, 2c+2), wave w owns c=2w,2w+1
#define STAGE(BUF, IT)                                                         \
    {                                                                          \
        const int kb_ = kslice0 + (IT) * KSTEP;                                \
        _Pragma("unroll")                                                      \
        for (int j = 0; j < 2; ++j) {                                          \
            const int c_ = w * 2 + j;                                          \
            const int o_ = 2 * c_ + (l >> 5);                                  \
            const size_t goff_ = (size_t)(obase + o_) * IN_DIM + kb_ + (l & 31) * 4; \
            gload16(&indices[goff_],  &Idx[BUF][c_ * 256]);                    \
            gload16(&residual[goff_], &Res[BUF][c_ * 256]);                    \
        }                                                                      \
    }

    STAGE(0, 0)
    __syncthreads();    // drains stage0 + cb + scs

    f32x4 acc = {0.f, 0.f, 0.f, 0.f};

    #pragma unroll
    for (int it = 0; it < NIT; ++it) {
        const int cur = it & 1;                 // compile-time under unroll
        if (it + 1 < NIT) STAGE(cur ^ 1, it + 1)

        // dequant: thread t -> quads (o = t>>5 [+8], k0 = (t&31)*4); reads are
        // the exact linear stage order -> bank-floor ds_read_b128
        {
            const int base = tid * 4;
            const int4   i0 = *reinterpret_cast<const int4*>(&Idx[cur][base]);
            const int4   i1 = *reinterpret_cast<const int4*>(&Idx[cur][base + 1024]);
            const float4 r0 = *reinterpret_cast<const float4*>(&Res[cur][base]);
            const float4 r1 = *reinterpret_cast<const float4*>(&Res[cur][base + 1024]);
            const int o0 = tid >> 5, o1 = o0 + 8;
            const float s0 = scs[o0][it], s1 = scs[o1][it];
            const float* c0 = &cb[o0 * LEVELS];
            const float* c1 = &cb[o1 * LEVELS];
            const int k0 = (tid & 31) * 4;
            const unsigned q00 = f2bf(fmaf(c0[i0.x], s0, r0.x)) | (f2bf(fmaf(c0[i0.y], s0, r0.y)) << 16);
            const unsigned q01 = f2bf(fmaf(c0[i0.z], s0, r0.z)) | (f2bf(fmaf(c0[i0.w], s0, r0.w)) << 16);
            const unsigned q10 = f2bf(fmaf(c1[i1.x], s1, r1.x)) | (f2bf(fmaf(c1[i1.y], s1, r1.y)) << 16);
            const unsigned q11 = f2bf(fmaf(c1[i1.z], s1, r1.z)) | (f2bf(fmaf(c1[i1.w], s1, r1.w)) << 16);
            *reinterpret_cast<uint2*>(&Wb[o0 * WB_S + k0]) = make_uint2(q00, q01);
            *reinterpret_cast<uint2*>(&Wb[o1 * WB_S + k0]) = make_uint2(q10, q11);
        }
        __syncthreads();    // Wb ready (also drains in-flight stage)

        // MFMA: wave w owns k-substep w of this 128-step
        {
            const bf16x8 b = *reinterpret_cast<const bf16x8*>(
                &Wb[(l & 15) * WB_S + w * 32 + ((l >> 4) << 3)]);
            acc = __builtin_amdgcn_mfma_f32_16x16x32_bf16(
                *reinterpret_cast<const bf16x8*>(&aA[it]), b, acc, 0, 0, 0);
        }
        __syncthreads();    // Wb reads done before next overwrite
    }
#undef STAGE

    // ---- epilogue: cross-wave k-substep reduce (reuse Wb as f32 buffer), atomics
    float* red = reinterpret_cast<float*>(Wb);      // 3 KiB needed, 4.25 available
    if (w > 0)
        *reinterpret_cast<f32x4*>(&red[((w - 1) * 64 + l) * 4]) = acc;
    __syncthreads();
    if (w == 0) {
        #pragma unroll
        for (int v = 0; v < 3; ++v)
            acc += *reinterpret_cast<const f32x4*>(&red[(v * 64 + l) * 4]);
        const int col = obase + (l & 15);
        const float bv = (kq == 0) ? bias[col] : 0.f;
        #pragma unroll
        for (int q = 0; q < 4; ++q) {
            const int m = ((l >> 4) << 2) + q;     // C/D row map [m89/m91]
            atomicAdd(&out[m * UNITS + col], acc[q] + bv);
        }
    }
}

// ---------- fallback (proven) if workspace too small ----------
__global__ __launch_bounds__(256, 4)
void fallback_kernel(const float* __restrict__ inputs,
                     const float* __restrict__ codebooks,
                     const float* __restrict__ scales,
                     const float* __restrict__ residual,
                     const float* __restrict__ bias,
                     const int*   __restrict__ indices,
                     float* __restrict__ out)
{
    __shared__ float cb[16 * LEVELS];
    const int tid = threadIdx.x;
    const int ub = blockIdx.x & 255, ks = blockIdx.x >> 8;
    const int o_block = ub * 16;
    cb[tid] = codebooks[o_block * LEVELS + tid];
    __syncthreads();
    const int wave = tid >> 6, lane = tid & 63;
    const int o0 = o_block + wave * 4;
    const int k = ks * 256 + lane * 4;
    const int g = k >> 7;
    int4 idx[4]; float4 r[4]; float s[4];
    #pragma unroll
    for (int u = 0; u < 4; ++u) {
        const size_t off = (size_t)(o0 + u) * IN_DIM + k;
        idx[u] = *reinterpret_cast<const int4*>(&indices[off]);
        r[u]   = *reinterpret_cast<const float4*>(&residual[off]);
        s[u]   = scales[(o0 + u) * NGROUPS + g];
    }
    const float* cbw = &cb[wave * 4 * LEVELS];
    float wv[4][4];
    #pragma unroll
    for (int u = 0; u < 4; ++u) {
        wv[u][0] = fmaf(cbw[u * LEVELS + idx[u].x], s[u], r[u].x);
        wv[u][1] = fmaf(cbw[u * LEVELS + idx[u].y], s[u], r[u].y);
        wv[u][2] = fmaf(cbw[u * LEVELS + idx[u].z], s[u], r[u].z);
        wv[u][3] = fmaf(cbw[u * LEVELS + idx[u].w], s[u], r[u].w);
    }
    float acc[64];
    #pragma unroll
    for (int b = 0; b < BATCH; ++b) {
        const float4 in4 = *reinterpret_cast<const float4*>(&inputs[b * IN_DIM + k]);
        #pragma unroll
        for (int u = 0; u < 4; ++u) {
            float a = in4.x * wv[u][0];
            a = fmaf(in4.y, wv[u][1], a);
            a = fmaf(in4.z, wv[u][2], a);
            a = fmaf(in4.w, wv[u][3], a);
            acc[b * 4 + u] = a;
        }
    }
#define FOLD(S, N)                                         \
    {                                                      \
        const bool hi = (lane & (S)) != 0;                 \
        _Pragma("unroll")                                  \
        for (int t = 0; t < (N) / 2; ++t) {                \
            float a  = acc[2 * t];                         \
            float b2 = acc[2 * t + 1];                     \
            float send = hi ? a : b2;                      \
            float recv = __shfl_xor(send, (S));            \
            acc[t] = (hi ? b2 : a) + recv;                 \
        }                                                  \
    }
    FOLD(1, 64) FOLD(2, 32) FOLD(4, 16) FOLD(8, 8) FOLD(16, 4) FOLD(32, 2)
#undef FOLD
    const int b_ = lane >> 2, u_ = lane & 3;
    float v = acc[0];
    if (ks == 0) v += bias[o0 + u_];
    atomicAdd(&out[b_ * UNITS + o0 + u_], v);
}

extern "C" void kernel_launch(void* const* d_in, const int* in_sizes, int n_in,
                              void* d_out, int out_size, void* d_ws, size_t ws_size,
                              hipStream_t stream)
{
    const float* inputs    = (const float*)d_in[0];
    const float* codebooks = (const float*)d_in[1];
    const float* scales    = (const float*)d_in[2];
    const float* residual  = (const float*)d_in[3];
    const float* bias      = (const float*)d_in[4];
    const int*   indices   = (const int*)d_in[5];
    float* out = (float*)d_out;

    hipMemsetAsync(d_out, 0, (size_t)out_size * sizeof(float), stream);

    const size_t need = (size_t)128 * 64 * 8 * sizeof(unsigned short); // 128 KiB
    if (ws_size >= need) {
        unsigned short* A_frag = (unsigned short*)d_ws;
        aconv_kernel<<<32, 256, 0, stream>>>(inputs, A_frag);
        turbo_mfma2<<<256 * KSPLIT, 256, 0, stream>>>(
            codebooks, scales, residual, bias, indices, A_frag, out);
    } else {
        fallback_kernel<<<256 * 16, 256, 0, stream>>>(
            inputs, codebooks, scales, residual, bias, indices, out);
    }
}